// Round 18
// baseline (81.561 us; speedup 1.0000x reference)
//
#include <hip/hip_runtime.h>

#define S_LEN 4096
#define B_SZ 8
#define HN_OFF 8388608      // 8*4096*256
#define CPROWS 544          // 8-elem rows per parity copy (zero-padded past 4096)

typedef __attribute__((ext_vector_type(8))) short short8;
typedef __attribute__((ext_vector_type(4))) float f32x4;

typedef const __attribute__((address_space(1))) unsigned int as1_u32;
typedef __attribute__((address_space(3))) unsigned int as3_u32;

__device__ __forceinline__ void gload16(const short* g, short* l) {
  __builtin_amdgcn_global_load_lds((as1_u32*)g, (as3_u32*)l, 16, 0, 0);
}

__device__ __forceinline__ short f2bf(float f) {
  union { float f; unsigned u; } v; v.f = f;
  unsigned r = v.u + 0x7FFFu + ((v.u >> 16) & 1u);
  return (short)(r >> 16);
}

#define MFMA(d, a, bb) d = __builtin_amdgcn_mfma_f32_16x16x32_bf16(a, bb, d, 0, 0, 0)

// K1 fused prep (R13, unchanged):
__global__ __launch_bounds__(256) void k_prep(const float* __restrict__ x,
                                              const float* __restrict__ Wu,
                                              const float* __restrict__ bu,
                                              const float* __restrict__ H,
                                              const float* __restrict__ Wh,
                                              short* __restrict__ cp,
                                              short* __restrict__ xb,
                                              short* __restrict__ Ht,
                                              short* __restrict__ wht) {
  int bx = blockIdx.x;
  if (bx >= 8520) {
    int j = (bx - 8520) * 256 + threadIdx.x;
    if (j < 256 * 384) {
      int n = j / 384, k = j % 384;
      wht[j] = f2bf(Wh[k * 256 + n]);
    }
    return;
  }
  if (bx >= 8264) {
    __shared__ short tile[64][72];
    int bx2 = bx - 8264;                 // 256 = tt(64) * qt(4)
    int t0 = (bx2 >> 2) << 6, q0 = (bx2 & 3) << 6;
    int tid = threadIdx.x;
    int r = tid >> 2, c0 = (tid & 3) << 4;
    const float* src = H + (size_t)(q0 + r) * S_LEN + t0 + c0;
    #pragma unroll
    for (int v4 = 0; v4 < 4; ++v4) {
      float4 hv = *(const float4*)(src + 4 * v4);
      tile[r][c0 + 4 * v4]     = f2bf(hv.x);
      tile[r][c0 + 4 * v4 + 1] = f2bf(hv.y);
      tile[r][c0 + 4 * v4 + 2] = f2bf(hv.z);
      tile[r][c0 + 4 * v4 + 3] = f2bf(hv.w);
    }
    __syncthreads();
    int s2 = tid >> 2, qc = (tid & 3) << 4;
    short8 o0, o1;
    #pragma unroll
    for (int j2 = 0; j2 < 8; ++j2) {
      o0[j2] = tile[qc + j2][s2];
      o1[j2] = tile[qc + 8 + j2][s2];
    }
    short* dst = Ht + (size_t)(t0 + s2) * 256 + q0 + qc;
    *(short8*)dst       = o0;
    *(short8*)(dst + 8) = o1;
    return;
  }
  if (bx >= 8192) {
    int idx = (bx - 8192) * 256 + threadIdx.x;
    if (idx < 18432) {
      int j = idx & 7;
      int r = 508 + ((idx >> 3) % 36);
      int rem = (idx >> 3) / 36;
      int p = rem & 7;
      int b = rem >> 3;
      int e = 8 * r + p + j;
      if (e >= S_LEN)
        cp[((size_t)(b * 8 + p) * CPROWS + r) * 8 + j] = 0;
    }
    return;
  }
  int row = bx * 4 + (threadIdx.x >> 6);   // b*4096 + t
  int l = threadIdx.x & 63;
  float2 xv = *(const float2*)(x + (size_t)row * 128 + 2 * l);
  float2 wv = *(const float2*)(Wu + 2 * l);
  float s = xv.x * wv.x + xv.y * wv.y;
  #pragma unroll
  for (int m = 32; m >= 1; m >>= 1) s += __shfl_xor(s, m, 64);
  unsigned pack = (((unsigned)f2bf(xv.y) & 0xFFFFu) << 16) | ((unsigned)f2bf(xv.x) & 0xFFFFu);
  *(unsigned*)(xb + (size_t)row * 128 + 2 * l) = pack;
  float v = s + bu[0];
  v = v > 0.0f ? v : 0.0f;
  short vb = f2bf(v);
  if (l < 8) {
    int t = row & (S_LEN - 1);
    int b = row >> 12;
    int e = (S_LEN - 1) - t;
    int p = l;
    if (e >= p) {
      int d = e - p;
      cp[((size_t)(b * 8 + p) * CPROWS + (d >> 3)) * 8 + (d & 7)] = vb;
    }
  }
}

// K2: Gt[n][t] = sum_q Wh[q,n]*H[q,t] (R13, unchanged)
__global__ __launch_bounds__(256) void k_g(const short* __restrict__ wht,
                                           const short* __restrict__ Ht,
                                           short* __restrict__ Gt) {
  int nt = blockIdx.x & 1, tt = blockIdx.x >> 1;
  int n0 = nt << 7, t0 = tt << 7;
  int tid = threadIdx.x;
  int lane = tid & 63, wid = tid >> 6;
  int wr = wid >> 1, wc = wid & 1;
  int lm = lane & 15, kg = lane >> 4;

  const short* Abase = wht + (size_t)(n0 + wr * 64 + lm) * 384 + 8 * kg;
  const short* Bbase = Ht  + (size_t)(t0 + wc * 64 + lm) * 256 + 8 * kg;

  f32x4 acc[4][4];
  #pragma unroll
  for (int ii = 0; ii < 4; ++ii)
    #pragma unroll
    for (int jn = 0; jn < 4; ++jn)
      acc[ii][jn] = (f32x4){0.0f, 0.0f, 0.0f, 0.0f};

  #pragma unroll
  for (int c = 0; c < 4; ++c) {
    short8 a[8], bf[8];
    #pragma unroll
    for (int mf = 0; mf < 4; ++mf)
      #pragma unroll
      for (int ks = 0; ks < 2; ++ks)
        a[mf * 2 + ks] = *(const short8*)(Abase + mf * 16 * 384 + c * 64 + ks * 32);
    #pragma unroll
    for (int nf = 0; nf < 4; ++nf)
      #pragma unroll
      for (int ks = 0; ks < 2; ++ks)
        bf[nf * 2 + ks] = *(const short8*)(Bbase + nf * 16 * 256 + c * 64 + ks * 32);
    #pragma unroll
    for (int ks = 0; ks < 2; ++ks)
      #pragma unroll
      for (int mf = 0; mf < 4; ++mf)
        #pragma unroll
        for (int nf = 0; nf < 4; ++nf)
          MFMA(acc[mf][nf], a[mf * 2 + ks], bf[nf * 2 + ks]);
  }

  #pragma unroll
  for (int mf = 0; mf < 4; ++mf)
    #pragma unroll
    for (int nf = 0; nf < 4; ++nf)
      #pragma unroll
      for (int j = 0; j < 4; ++j) {
        int n = n0 + wr * 64 + mf * 16 + kg * 4 + j;
        int t = t0 + wc * 64 + nf * 16 + lm;
        Gt[(size_t)n * S_LEN + t] = f2bf(acc[mf][nf][j]);
      }
}

// K3 fused: h[s,n] = relu(Toeplitz(u)@Gt^T + x@Whx + bh).
// 512 equal blocks (kk,nq,b) x TWO waves; two tiles 128(s)x64(n) (st=31-kk
// then st=kk) -> 33 T-chunks (BK-128) + 4 x half-chunks. Wave tile 64x64:
// per-wave reads = 10 A + 16 B per 64 MFMA (0.41 KB/MFMA, -28% LDS volume
// vs R17). Ring-2 LDS 40KB, R12-proven single-barrier discipline:
// vmcnt(0)+lgkmcnt(0)+barrier at chunk top, STAGE(c+1) issued after.
__global__ __launch_bounds__(128) void k_fused(const short* __restrict__ cp,
                                               const short* __restrict__ Gt,
                                               const short* __restrict__ xb,
                                               const short* __restrict__ wht,
                                               const float* __restrict__ bh,
                                               float* __restrict__ out) {
  __shared__ __attribute__((aligned(16))) short Bt[2][64 * 128];  // 32 KB
  __shared__ __attribute__((aligned(16))) short Aw[2][2048];      // 8 KB

  int i = blockIdx.x;                 // 512 = kk(16) * nq(4) * b(8)
  int kk = i >> 5;
  int nq = (i >> 3) & 3;
  int b  = i & 7;
  int n0 = nq << 6;

  int tid = threadIdx.x;
  int lane = tid & 63, wid = tid >> 6;   // 2 waves; wid = s-half
  int lm = lane & 15, kg = lane >> 4;
  int l3 = lane >> 3, l7 = lane & 7;
  int lm7 = lm & 7;

  // B staging: wave stages rows wid*32..+31 (n), 8 gloads of 4 rows.
  // e even rows 8j+kg (key kg); e odd rows 8j+4+kg (key kg|4).
  const short* bSe = Gt + (size_t)(n0 + wid * 32 + kg) * S_LEN + ((lm ^ kg) << 3);
  const short* bSo = Gt + (size_t)(n0 + wid * 32 + 4 + kg) * S_LEN + ((lm ^ (kg | 4)) << 3);

  // A-frag swizzled offsets (R13 BK-128 dedup): frag(mf,ks) -> v = 2ks-mf+3
  int dbase = 127 - 64 * wid - lm + 8 * kg;
  int aof[10];
  #pragma unroll
  for (int v = 0; v < 10; ++v) {
    int d = dbase + 16 * v - 48;
    aof[v] = ((d & ~7) | ((d & 7) ^ ((d >> 3) & 7))) << 3;   // shorts
  }

  // B-frag offsets: row nf*16+lm (nf 0..3), data chunk 4ks+kg, key lm7
  int bof[4][4];
  #pragma unroll
  for (int nf = 0; nf < 4; ++nf)
    #pragma unroll
    for (int ks = 0; ks < 4; ++ks)
      bof[nf][ks] = (nf * 16 + lm) * 128 + (((4 * ks + kg) ^ lm7) << 3);

  // x A-frag offsets: row wid*64+mf*16+lm of [128 s][64 d] tile, chunk ks*4+kg
  int xof[4][2];
  #pragma unroll
  for (int mf = 0; mf < 4; ++mf)
    #pragma unroll
    for (int ks = 0; ks < 2; ++ks)
      xof[mf][ks] = (wid * 64 + mf * 16 + lm) * 64 + (((4 * ks + kg) ^ lm7) << 3);

  for (int ph = 0; ph < 2; ++ph) {
    int st = ph ? kk : (31 - kk);
    int s0 = st << 7;
    int asbase = 496 - 16 * st;
    // A staging: 2 gloads/wave, rows asbase + wid*16 + 8e + l3, parity (l7^l3)
    const short* aSrc = cp + ((size_t)(b * 8 + (l7 ^ l3)) * CPROWS + asbase + wid * 16 + l3) * 8;
    // x staging: 8 gloads/wave, rows s0 + wid*64 + 8j + l3, key l3
    const short* xS = xb + (size_t)(b * S_LEN + s0 + wid * 64 + l3) * 128 + ((l7 ^ l3) << 3);

    int NT = st + 1;           // Toeplitz BK-128 chunks
    int NC = NT + 2;           // + 2 x BK-64 half-chunks

    f32x4 acc[4][4];
    #pragma unroll
    for (int ii = 0; ii < 4; ++ii)
      #pragma unroll
      for (int jn = 0; jn < 4; ++jn)
        acc[ii][jn] = (f32x4){0.0f, 0.0f, 0.0f, 0.0f};

    auto STAGE = [&](int cc) {
      int slot = cc & 1;
      if (cc < NT) {
        int coff = cc * 128;
        #pragma unroll
        for (int j = 0; j < 4; ++j) {
          gload16(bSe + (size_t)(8 * j) * S_LEN + coff, &Bt[slot][(wid * 32 + 8 * j) * 128]);
          gload16(bSo + (size_t)(8 * j) * S_LEN + coff, &Bt[slot][(wid * 32 + 8 * j + 4) * 128]);
        }
        gload16(aSrc + coff,       &Aw[slot][(wid * 2) * 512]);
        gload16(aSrc + 64 + coff,  &Aw[slot][(wid * 2 + 1) * 512]);
      } else {
        int dc = cc - NT;
        #pragma unroll
        for (int j = 0; j < 8; ++j)
          gload16(xS + (size_t)(8 * j) * 128 + dc * 64, &Bt[slot][(wid * 64 + 8 * j) * 64]);
      }
    };

    if (ph) asm volatile("s_waitcnt vmcnt(0) lgkmcnt(0)\n\ts_barrier" ::: "memory");
    STAGE(0);

    for (int c = 0; c < NC; ++c) {
      asm volatile("s_waitcnt vmcnt(0) lgkmcnt(0)\n\ts_barrier" ::: "memory");
      if (c + 1 < NC) STAGE(c + 1);

      if (c < NT) {
        const short* AwB = &Aw[c & 1][0];
        const short* BtB = &Bt[c & 1][0];
        short8 A10[10];
        #pragma unroll
        for (int v = 0; v < 10; ++v) A10[v] = *(const short8*)(AwB + aof[v]);
        __builtin_amdgcn_s_setprio(1);
        #pragma unroll
        for (int ks = 0; ks < 4; ++ks) {
          short8 B0 = *(const short8*)(BtB + bof[0][ks]);
          short8 B1 = *(const short8*)(BtB + bof[1][ks]);
          short8 B2 = *(const short8*)(BtB + bof[2][ks]);
          short8 B3 = *(const short8*)(BtB + bof[3][ks]);
          #pragma unroll
          for (int mf = 0; mf < 4; ++mf) {
            short8 a = A10[2 * ks - mf + 3];
            MFMA(acc[mf][0], a, B0);
            MFMA(acc[mf][1], a, B1);
            MFMA(acc[mf][2], a, B2);
            MFMA(acc[mf][3], a, B3);
          }
        }
        __builtin_amdgcn_s_setprio(0);
      } else {
        int dc = c - NT;
        const short* BtB = &Bt[c & 1][0];
        short8 Ax[4][2];
        #pragma unroll
        for (int mf = 0; mf < 4; ++mf)
          #pragma unroll
          for (int ks = 0; ks < 2; ++ks)
            Ax[mf][ks] = *(const short8*)(BtB + xof[mf][ks]);
        short8 Bx[2][4];
        #pragma unroll
        for (int ks = 0; ks < 2; ++ks)
          #pragma unroll
          for (int nf = 0; nf < 4; ++nf)
            Bx[ks][nf] = *(const short8*)(wht + (size_t)(n0 + nf * 16 + lm) * 384
                                          + 256 + dc * 64 + ks * 32 + kg * 8);
        __builtin_amdgcn_s_setprio(1);
        #pragma unroll
        for (int ks = 0; ks < 2; ++ks)
          #pragma unroll
          for (int mf = 0; mf < 4; ++mf)
            #pragma unroll
            for (int nf = 0; nf < 4; ++nf)
              MFMA(acc[mf][nf], Ax[mf][ks], Bx[ks][nf]);
        __builtin_amdgcn_s_setprio(0);
      }
    }

    // Epilogue: bias + relu + f32 store (+ h_n for s==4095)
    #pragma unroll
    for (int mf = 0; mf < 4; ++mf)
      #pragma unroll
      for (int nf = 0; nf < 4; ++nf) {
        int n = n0 + nf * 16 + lm;
        float bias = bh[n];
        #pragma unroll
        for (int j2 = 0; j2 < 4; ++j2) {
          int s = s0 + wid * 64 + mf * 16 + kg * 4 + j2;
          float v = acc[mf][nf][j2] + bias;
          v = v > 0.0f ? v : 0.0f;
          out[(size_t)(b * S_LEN + s) * 256 + n] = v;
          if (s == S_LEN - 1)
            out[HN_OFF + b * 256 + n] = v;
        }
      }
  }
}

extern "C" void kernel_launch(void* const* d_in, const int* in_sizes, int n_in,
                              void* d_out, int out_size, void* d_ws, size_t ws_size,
                              hipStream_t stream) {
  const float* x  = (const float*)d_in[0];
  const float* Wu = (const float*)d_in[1];
  const float* bu = (const float*)d_in[2];
  const float* Wh = (const float*)d_in[3];
  const float* bh = (const float*)d_in[4];
  const float* H  = (const float*)d_in[5];
  float* out = (float*)d_out;

  char* ws = (char*)d_ws;
  short* cp  = (short*)(ws);                       // 557056 B
  short* wht = (short*)(ws + 557056);              // 196608 B
  short* xb  = (short*)(ws + 753664);              // 8388608 B
  short* Ht  = (short*)(ws + 9142272);             // 2097152 B
  short* Gt  = (short*)(ws + 11239424);            // 2097152 B (end 13336576)

  k_prep<<<8904, 256, 0, stream>>>(x, Wu, bu, H, Wh, cp, xb, Ht, wht);
  k_g   <<<64,   256, 0, stream>>>(wht, Ht, Gt);
  k_fused<<<512, 128, 0, stream>>>(cp, Gt, xb, wht, bh, out);
}

// Round 19
// 66.525 us; speedup vs baseline: 1.2260x; 1.2260x over previous
//
#include <hip/hip_runtime.h>

#define S_LEN 4096
#define B_SZ 8
#define HN_OFF 8388608      // 8*4096*256
#define CPROWS 544          // 8-elem rows per parity copy (zero-padded past 4096)

typedef __attribute__((ext_vector_type(8))) short short8;
typedef __attribute__((ext_vector_type(4))) float f32x4;

typedef const __attribute__((address_space(1))) unsigned int as1_u32;
typedef __attribute__((address_space(3))) unsigned int as3_u32;

__device__ __forceinline__ void gload16(const short* g, short* l) {
  __builtin_amdgcn_global_load_lds((as1_u32*)g, (as3_u32*)l, 16, 0, 0);
}

__device__ __forceinline__ short f2bf(float f) {
  union { float f; unsigned u; } v; v.f = f;
  unsigned r = v.u + 0x7FFFu + ((v.u >> 16) & 1u);
  return (short)(r >> 16);
}

#define MFMA(d, a, bb) d = __builtin_amdgcn_mfma_f32_16x16x32_bf16(a, bb, d, 0, 0, 0)

// K1 fused prep:
//  [0,8192):      u = relu(x@W_u+b_u) -> 8 parity copies cp; x -> bf16 xb rows
//  [8192,8264):   zero e>=4096 tail of cp
//  [8264,8520):   H [256 q][4096 t] -> Ht bf16 [4096 t][256 q] (64x64 LDS transpose)
//  [8520,8544):   W_h [384 k][256 n] -> wht bf16 [256 n][384 k] (64x64 LDS transpose,
//                 coalesced — replaces the old strided scalar path)
__global__ __launch_bounds__(256) void k_prep(const float* __restrict__ x,
                                              const float* __restrict__ Wu,
                                              const float* __restrict__ bu,
                                              const float* __restrict__ H,
                                              const float* __restrict__ Wh,
                                              short* __restrict__ cp,
                                              short* __restrict__ xb,
                                              short* __restrict__ Ht,
                                              short* __restrict__ wht) {
  int bx = blockIdx.x;
  if (bx >= 8520) {
    // Wh transpose: 24 blocks = kt(6) * nt(4); tile 64(k) x 64(n)
    __shared__ short tile[64][72];
    int bx2 = bx - 8520;
    int k0 = (bx2 >> 2) << 6, n0 = (bx2 & 3) << 6;
    int tid = threadIdx.x;
    int r = tid >> 2, c0 = (tid & 3) << 4;   // r: k-row 0..63; c0: n-col group
    const float* src = Wh + (size_t)(k0 + r) * 256 + n0 + c0;
    #pragma unroll
    for (int v4 = 0; v4 < 4; ++v4) {
      float4 wv = *(const float4*)(src + 4 * v4);
      tile[r][c0 + 4 * v4]     = f2bf(wv.x);
      tile[r][c0 + 4 * v4 + 1] = f2bf(wv.y);
      tile[r][c0 + 4 * v4 + 2] = f2bf(wv.z);
      tile[r][c0 + 4 * v4 + 3] = f2bf(wv.w);
    }
    __syncthreads();
    int n2 = tid >> 2, kc = (tid & 3) << 4;  // n2: n-row 0..63; kc: k-col group
    short8 o0, o1;
    #pragma unroll
    for (int j2 = 0; j2 < 8; ++j2) {
      o0[j2] = tile[kc + j2][n2];
      o1[j2] = tile[kc + 8 + j2][n2];
    }
    short* dst = wht + (size_t)(n0 + n2) * 384 + k0 + kc;
    *(short8*)dst       = o0;
    *(short8*)(dst + 8) = o1;
    return;
  }
  if (bx >= 8264) {
    __shared__ short tile[64][72];
    int bx2 = bx - 8264;                 // 256 = tt(64) * qt(4)
    int t0 = (bx2 >> 2) << 6, q0 = (bx2 & 3) << 6;
    int tid = threadIdx.x;
    int r = tid >> 2, c0 = (tid & 3) << 4;
    const float* src = H + (size_t)(q0 + r) * S_LEN + t0 + c0;
    #pragma unroll
    for (int v4 = 0; v4 < 4; ++v4) {
      float4 hv = *(const float4*)(src + 4 * v4);
      tile[r][c0 + 4 * v4]     = f2bf(hv.x);
      tile[r][c0 + 4 * v4 + 1] = f2bf(hv.y);
      tile[r][c0 + 4 * v4 + 2] = f2bf(hv.z);
      tile[r][c0 + 4 * v4 + 3] = f2bf(hv.w);
    }
    __syncthreads();
    int s2 = tid >> 2, qc = (tid & 3) << 4;
    short8 o0, o1;
    #pragma unroll
    for (int j2 = 0; j2 < 8; ++j2) {
      o0[j2] = tile[qc + j2][s2];
      o1[j2] = tile[qc + 8 + j2][s2];
    }
    short* dst = Ht + (size_t)(t0 + s2) * 256 + q0 + qc;
    *(short8*)dst       = o0;
    *(short8*)(dst + 8) = o1;
    return;
  }
  if (bx >= 8192) {
    int idx = (bx - 8192) * 256 + threadIdx.x;
    if (idx < 18432) {
      int j = idx & 7;
      int r = 508 + ((idx >> 3) % 36);
      int rem = (idx >> 3) / 36;
      int p = rem & 7;
      int b = rem >> 3;
      int e = 8 * r + p + j;
      if (e >= S_LEN)
        cp[((size_t)(b * 8 + p) * CPROWS + r) * 8 + j] = 0;
    }
    return;
  }
  int row = bx * 4 + (threadIdx.x >> 6);   // b*4096 + t
  int l = threadIdx.x & 63;
  float2 xv = *(const float2*)(x + (size_t)row * 128 + 2 * l);
  float2 wv = *(const float2*)(Wu + 2 * l);
  float s = xv.x * wv.x + xv.y * wv.y;
  #pragma unroll
  for (int m = 32; m >= 1; m >>= 1) s += __shfl_xor(s, m, 64);
  unsigned pack = (((unsigned)f2bf(xv.y) & 0xFFFFu) << 16) | ((unsigned)f2bf(xv.x) & 0xFFFFu);
  *(unsigned*)(xb + (size_t)row * 128 + 2 * l) = pack;
  float v = s + bu[0];
  v = v > 0.0f ? v : 0.0f;
  short vb = f2bf(v);
  if (l < 8) {
    int t = row & (S_LEN - 1);
    int b = row >> 12;
    int e = (S_LEN - 1) - t;
    int p = l;
    if (e >= p) {
      int d = e - p;
      cp[((size_t)(b * 8 + p) * CPROWS + (d >> 3)) * 8 + (d & 7)] = vb;
    }
  }
}

// K2: Gt[n][t] = sum_q Wh[q,n]*H[q,t] (R13/R17, unchanged)
__global__ __launch_bounds__(256) void k_g(const short* __restrict__ wht,
                                           const short* __restrict__ Ht,
                                           short* __restrict__ Gt) {
  int nt = blockIdx.x & 1, tt = blockIdx.x >> 1;
  int n0 = nt << 7, t0 = tt << 7;
  int tid = threadIdx.x;
  int lane = tid & 63, wid = tid >> 6;
  int wr = wid >> 1, wc = wid & 1;
  int lm = lane & 15, kg = lane >> 4;

  const short* Abase = wht + (size_t)(n0 + wr * 64 + lm) * 384 + 8 * kg;
  const short* Bbase = Ht  + (size_t)(t0 + wc * 64 + lm) * 256 + 8 * kg;

  f32x4 acc[4][4];
  #pragma unroll
  for (int ii = 0; ii < 4; ++ii)
    #pragma unroll
    for (int jn = 0; jn < 4; ++jn)
      acc[ii][jn] = (f32x4){0.0f, 0.0f, 0.0f, 0.0f};

  #pragma unroll
  for (int c = 0; c < 4; ++c) {
    short8 a[8], bf[8];
    #pragma unroll
    for (int mf = 0; mf < 4; ++mf)
      #pragma unroll
      for (int ks = 0; ks < 2; ++ks)
        a[mf * 2 + ks] = *(const short8*)(Abase + mf * 16 * 384 + c * 64 + ks * 32);
    #pragma unroll
    for (int nf = 0; nf < 4; ++nf)
      #pragma unroll
      for (int ks = 0; ks < 2; ++ks)
        bf[nf * 2 + ks] = *(const short8*)(Bbase + nf * 16 * 256 + c * 64 + ks * 32);
    #pragma unroll
    for (int ks = 0; ks < 2; ++ks)
      #pragma unroll
      for (int mf = 0; mf < 4; ++mf)
        #pragma unroll
        for (int nf = 0; nf < 4; ++nf)
          MFMA(acc[mf][nf], a[mf * 2 + ks], bf[nf * 2 + ks]);
  }

  #pragma unroll
  for (int mf = 0; mf < 4; ++mf)
    #pragma unroll
    for (int nf = 0; nf < 4; ++nf)
      #pragma unroll
      for (int j = 0; j < 4; ++j) {
        int n = n0 + wr * 64 + mf * 16 + kg * 4 + j;
        int t = t0 + wc * 64 + nf * 16 + lm;
        Gt[(size_t)n * S_LEN + t] = f2bf(acc[mf][nf][j]);
      }
}

// K3 fused (R17 verbatim — best measured: 47.3us):
// 512 IDENTICAL blocks (kk,nq,b) x 4 waves: two tiles 128(s)x64(n)
// (st=31-kk then st=kk) -> every block 33 T-chunks (BK-128) + 4 x-chunks
// (BK-64). Equal blocks => any 2 co-resident blocks overlap end-to-end,
// placement-independent. Ring-4 LDS 80KB -> 2 blocks/CU. R3 discipline:
// STAGE(c+2) before counted wait vmcnt(10/5/0)+lgkmcnt(0), one barrier/chunk.
__global__ __launch_bounds__(256, 2) void k_fused(const short* __restrict__ cp,
                                                  const short* __restrict__ Gt,
                                                  const short* __restrict__ xb,
                                                  const short* __restrict__ wht,
                                                  const float* __restrict__ bh,
                                                  float* __restrict__ out) {
  __shared__ __attribute__((aligned(16))) short Bt[4][64 * 128];  // 64 KB
  __shared__ __attribute__((aligned(16))) short Aw[4][2048];      // 16 KB

  int i = blockIdx.x;                 // 512 = kk(16) * nq(4) * b(8)
  int kk = i >> 5;
  int nq = (i >> 3) & 3;
  int b  = i & 7;
  int n0 = nq << 6;

  int tid = threadIdx.x;
  int lane = tid & 63, wid = tid >> 6;
  int wr = wid >> 1, wc = wid & 1;      // wave tile 64(s) x 32(n)
  int lm = lane & 15, kg = lane >> 4;
  int l3 = lane >> 3, l7 = lane & 7;
  int lm7 = lm & 7;

  const short* bS0 = Gt + (size_t)(n0 + wid * 16 + kg) * S_LEN + ((lm ^ kg) << 3);
  const short* bS1 = Gt + (size_t)(n0 + wid * 16 + 4 + kg) * S_LEN + ((lm ^ (kg | 4)) << 3);

  int dbase = 127 - 64 * wr - lm + 8 * kg;
  int aof[10];
  #pragma unroll
  for (int v = 0; v < 10; ++v) {
    int d = dbase + 16 * v - 48;
    aof[v] = ((d & ~7) | ((d & 7) ^ ((d >> 3) & 7))) << 3;   // shorts
  }

  int bof[8];
  #pragma unroll
  for (int nf = 0; nf < 2; ++nf)
    #pragma unroll
    for (int ks = 0; ks < 4; ++ks)
      bof[nf * 4 + ks] = (wc * 32 + nf * 16 + lm) * 128 + (((4 * ks + kg) ^ lm7) << 3);

  int xof[4][2];
  #pragma unroll
  for (int mf = 0; mf < 4; ++mf)
    #pragma unroll
    for (int ks = 0; ks < 2; ++ks)
      xof[mf][ks] = (wr * 64 + mf * 16 + lm) * 64 + (((4 * ks + kg) ^ lm7) << 3);

  for (int ph = 0; ph < 2; ++ph) {
    int st = ph ? kk : (31 - kk);
    int s0 = st << 7;
    int asbase = 496 - 16 * st;
    const short* aSrc = cp + ((size_t)(b * 8 + (l7 ^ l3)) * CPROWS + asbase + wid * 8 + l3) * 8;
    const short* xS = xb + (size_t)(b * S_LEN + s0 + wid * 32 + l3) * 128 + ((l7 ^ l3) << 3);

    int NT = st + 1;           // Toeplitz BK-128 chunks
    int NC = NT + 2;           // + 2 x BK-64 chunks

    f32x4 acc[4][2];
    #pragma unroll
    for (int ii = 0; ii < 4; ++ii)
      #pragma unroll
      for (int jn = 0; jn < 2; ++jn)
        acc[ii][jn] = (f32x4){0.0f, 0.0f, 0.0f, 0.0f};

    auto STAGE = [&](int cc) {
      int slot = cc & 3;
      if (cc < NT) {
        int coff = cc * 128;
        gload16(bS0 + coff,                      &Bt[slot][(wid * 16) * 128]);
        gload16(bS1 + coff,                      &Bt[slot][(wid * 16 + 4) * 128]);
        gload16(bS0 + (size_t)8 * S_LEN + coff,  &Bt[slot][(wid * 16 + 8) * 128]);
        gload16(bS1 + (size_t)8 * S_LEN + coff,  &Bt[slot][(wid * 16 + 12) * 128]);
        gload16(aSrc + coff,                     &Aw[slot][wid * 512]);
      } else {
        int dc = cc - NT;
        #pragma unroll
        for (int jj = 0; jj < 4; ++jj)
          gload16(xS + (size_t)(8 * jj) * 128 + dc * 64, &Bt[slot][(wid * 32 + 8 * jj) * 64]);
        gload16(aSrc, &Aw[slot][wid * 512]);   // dummy: uniform 5 loads/chunk
      }
    };

    if (ph) asm volatile("s_waitcnt vmcnt(0) lgkmcnt(0)\n\ts_barrier" ::: "memory");
    STAGE(0);
    STAGE(1);

    for (int c = 0; c < NC; ++c) {
      if (c + 2 < NC) {
        STAGE(c + 2);
        asm volatile("s_waitcnt vmcnt(10) lgkmcnt(0)\n\ts_barrier" ::: "memory");
      } else if (c + 1 < NC) {
        asm volatile("s_waitcnt vmcnt(5) lgkmcnt(0)\n\ts_barrier" ::: "memory");
      } else {
        asm volatile("s_waitcnt vmcnt(0) lgkmcnt(0)\n\ts_barrier" ::: "memory");
      }

      if (c < NT) {
        const short* AwB = &Aw[c & 3][0];
        const short* BtB = &Bt[c & 3][0];
        short8 A10[10];
        #pragma unroll
        for (int v = 0; v < 10; ++v) A10[v] = *(const short8*)(AwB + aof[v]);
        short8 Bf[8];
        #pragma unroll
        for (int ii = 0; ii < 8; ++ii) Bf[ii] = *(const short8*)(BtB + bof[ii]);
        __builtin_amdgcn_s_setprio(1);
        #pragma unroll
        for (int ks = 0; ks < 4; ++ks)
          #pragma unroll
          for (int mf = 0; mf < 4; ++mf)
            #pragma unroll
            for (int nf = 0; nf < 2; ++nf)
              MFMA(acc[mf][nf], A10[2 * ks - mf + 3], Bf[nf * 4 + ks]);
        __builtin_amdgcn_s_setprio(0);
      } else {
        int dc = c - NT;
        const short* BtB = &Bt[c & 3][0];
        short8 Ax[4][2];
        #pragma unroll
        for (int mf = 0; mf < 4; ++mf)
          #pragma unroll
          for (int ks = 0; ks < 2; ++ks)
            Ax[mf][ks] = *(const short8*)(BtB + xof[mf][ks]);
        short8 Bx[2][2];
        #pragma unroll
        for (int ks = 0; ks < 2; ++ks)
          #pragma unroll
          for (int nf = 0; nf < 2; ++nf)
            Bx[ks][nf] = *(const short8*)(wht + (size_t)(n0 + wc * 32 + nf * 16 + lm) * 384
                                          + 256 + dc * 64 + ks * 32 + kg * 8);
        __builtin_amdgcn_s_setprio(1);
        #pragma unroll
        for (int ks = 0; ks < 2; ++ks)
          #pragma unroll
          for (int mf = 0; mf < 4; ++mf)
            #pragma unroll
            for (int nf = 0; nf < 2; ++nf)
              MFMA(acc[mf][nf], Ax[mf][ks], Bx[ks][nf]);
        __builtin_amdgcn_s_setprio(0);
      }
    }

    // Epilogue: bias + relu + f32 store (+ h_n for s==4095)
    #pragma unroll
    for (int mf = 0; mf < 4; ++mf)
      #pragma unroll
      for (int nf = 0; nf < 2; ++nf) {
        int n = n0 + wc * 32 + nf * 16 + lm;
        float bias = bh[n];
        #pragma unroll
        for (int j2 = 0; j2 < 4; ++j2) {
          int s = s0 + wr * 64 + mf * 16 + kg * 4 + j2;
          float v = acc[mf][nf][j2] + bias;
          v = v > 0.0f ? v : 0.0f;
          out[(size_t)(b * S_LEN + s) * 256 + n] = v;
          if (s == S_LEN - 1)
            out[HN_OFF + b * 256 + n] = v;
        }
      }
  }
}

extern "C" void kernel_launch(void* const* d_in, const int* in_sizes, int n_in,
                              void* d_out, int out_size, void* d_ws, size_t ws_size,
                              hipStream_t stream) {
  const float* x  = (const float*)d_in[0];
  const float* Wu = (const float*)d_in[1];
  const float* bu = (const float*)d_in[2];
  const float* Wh = (const float*)d_in[3];
  const float* bh = (const float*)d_in[4];
  const float* H  = (const float*)d_in[5];
  float* out = (float*)d_out;

  char* ws = (char*)d_ws;
  short* cp  = (short*)(ws);                       // 557056 B
  short* wht = (short*)(ws + 557056);              // 196608 B
  short* xb  = (short*)(ws + 753664);              // 8388608 B
  short* Ht  = (short*)(ws + 9142272);             // 2097152 B
  short* Gt  = (short*)(ws + 11239424);            // 2097152 B (end 13336576)

  k_prep<<<8544, 256, 0, stream>>>(x, Wu, bu, H, Wh, cp, xb, Ht, wht);
  k_g   <<<64,   256, 0, stream>>>(wht, Ht, Gt);
  k_fused<<<512, 256, 0, stream>>>(cp, Gt, xb, wht, bh, out);
}

// Round 20
// 64.729 us; speedup vs baseline: 1.2600x; 1.0277x over previous
//
#include <hip/hip_runtime.h>

#define S_LEN 4096
#define B_SZ 8
#define HN_OFF 8388608      // 8*4096*256
#define CPROWS 544          // 8-elem rows per parity copy (zero-padded past 4096)

typedef __attribute__((ext_vector_type(8))) short short8;
typedef __attribute__((ext_vector_type(4))) float f32x4;

typedef const __attribute__((address_space(1))) unsigned int as1_u32;
typedef __attribute__((address_space(3))) unsigned int as3_u32;

__device__ __forceinline__ void gload16(const short* g, short* l) {
  __builtin_amdgcn_global_load_lds((as1_u32*)g, (as3_u32*)l, 16, 0, 0);
}

__device__ __forceinline__ short f2bf(float f) {
  union { float f; unsigned u; } v; v.f = f;
  unsigned r = v.u + 0x7FFFu + ((v.u >> 16) & 1u);
  return (short)(r >> 16);
}

#define MFMA(d, a, bb) d = __builtin_amdgcn_mfma_f32_16x16x32_bf16(a, bb, d, 0, 0, 0)

// K1 fused prep:
//  [0,2048):     u = relu(x@W_u+b_u) -> 8 parity copies cp; x -> bf16 xb rows.
//                16 lanes/row (2x float4/lane), 4-stage 16-lane butterfly,
//                16 rows/block -> 2048 blocks (was 8192 1-wave-per-row).
//  [2048,2120):  zero e>=4096 tail of cp
//  [2120,2376):  H [256 q][4096 t] -> Ht bf16 [4096 t][256 q] (64x64 LDS transpose)
//  [2376,2400):  W_h [384 k][256 n] -> wht bf16 [256 n][384 k] (64x64 LDS transpose)
__global__ __launch_bounds__(256) void k_prep(const float* __restrict__ x,
                                              const float* __restrict__ Wu,
                                              const float* __restrict__ bu,
                                              const float* __restrict__ H,
                                              const float* __restrict__ Wh,
                                              short* __restrict__ cp,
                                              short* __restrict__ xb,
                                              short* __restrict__ Ht,
                                              short* __restrict__ wht) {
  int bx = blockIdx.x;
  if (bx >= 2376) {
    // Wh transpose: 24 blocks = kt(6) * nt(4); tile 64(k) x 64(n)
    __shared__ short tile[64][72];
    int bx2 = bx - 2376;
    int k0 = (bx2 >> 2) << 6, n0 = (bx2 & 3) << 6;
    int tid = threadIdx.x;
    int r = tid >> 2, c0 = (tid & 3) << 4;
    const float* src = Wh + (size_t)(k0 + r) * 256 + n0 + c0;
    #pragma unroll
    for (int v4 = 0; v4 < 4; ++v4) {
      float4 wv = *(const float4*)(src + 4 * v4);
      tile[r][c0 + 4 * v4]     = f2bf(wv.x);
      tile[r][c0 + 4 * v4 + 1] = f2bf(wv.y);
      tile[r][c0 + 4 * v4 + 2] = f2bf(wv.z);
      tile[r][c0 + 4 * v4 + 3] = f2bf(wv.w);
    }
    __syncthreads();
    int n2 = tid >> 2, kc = (tid & 3) << 4;
    short8 o0, o1;
    #pragma unroll
    for (int j2 = 0; j2 < 8; ++j2) {
      o0[j2] = tile[kc + j2][n2];
      o1[j2] = tile[kc + 8 + j2][n2];
    }
    short* dst = wht + (size_t)(n0 + n2) * 384 + k0 + kc;
    *(short8*)dst       = o0;
    *(short8*)(dst + 8) = o1;
    return;
  }
  if (bx >= 2120) {
    __shared__ short tile[64][72];
    int bx2 = bx - 2120;                 // 256 = tt(64) * qt(4)
    int t0 = (bx2 >> 2) << 6, q0 = (bx2 & 3) << 6;
    int tid = threadIdx.x;
    int r = tid >> 2, c0 = (tid & 3) << 4;
    const float* src = H + (size_t)(q0 + r) * S_LEN + t0 + c0;
    #pragma unroll
    for (int v4 = 0; v4 < 4; ++v4) {
      float4 hv = *(const float4*)(src + 4 * v4);
      tile[r][c0 + 4 * v4]     = f2bf(hv.x);
      tile[r][c0 + 4 * v4 + 1] = f2bf(hv.y);
      tile[r][c0 + 4 * v4 + 2] = f2bf(hv.z);
      tile[r][c0 + 4 * v4 + 3] = f2bf(hv.w);
    }
    __syncthreads();
    int s2 = tid >> 2, qc = (tid & 3) << 4;
    short8 o0, o1;
    #pragma unroll
    for (int j2 = 0; j2 < 8; ++j2) {
      o0[j2] = tile[qc + j2][s2];
      o1[j2] = tile[qc + 8 + j2][s2];
    }
    short* dst = Ht + (size_t)(t0 + s2) * 256 + q0 + qc;
    *(short8*)dst       = o0;
    *(short8*)(dst + 8) = o1;
    return;
  }
  if (bx >= 2048) {
    int idx = (bx - 2048) * 256 + threadIdx.x;
    if (idx < 18432) {
      int j = idx & 7;
      int r = 508 + ((idx >> 3) % 36);
      int rem = (idx >> 3) / 36;
      int p = rem & 7;
      int b = rem >> 3;
      int e = 8 * r + p + j;
      if (e >= S_LEN)
        cp[((size_t)(b * 8 + p) * CPROWS + r) * 8 + j] = 0;
    }
    return;
  }
  // u-section: 16 rows/block, 16 lanes/row
  int row = bx * 16 + (threadIdx.x >> 4);   // b*4096 + t
  int lq = threadIdx.x & 15;
  const float* xr = x + (size_t)row * 128 + lq * 8;
  float4 x0 = *(const float4*)xr;
  float4 x1 = *(const float4*)(xr + 4);
  const float* wr_ = Wu + lq * 8;
  float4 w0 = *(const float4*)wr_;
  float4 w1 = *(const float4*)(wr_ + 4);
  float s = x0.x * w0.x + x0.y * w0.y + x0.z * w0.z + x0.w * w0.w
          + x1.x * w1.x + x1.y * w1.y + x1.z * w1.z + x1.w * w1.w;
  #pragma unroll
  for (int m = 8; m >= 1; m >>= 1) s += __shfl_xor(s, m, 64);
  short8 pk;
  pk[0] = f2bf(x0.x); pk[1] = f2bf(x0.y); pk[2] = f2bf(x0.z); pk[3] = f2bf(x0.w);
  pk[4] = f2bf(x1.x); pk[5] = f2bf(x1.y); pk[6] = f2bf(x1.z); pk[7] = f2bf(x1.w);
  *(short8*)(xb + (size_t)row * 128 + lq * 8) = pk;
  float v = s + bu[0];
  v = v > 0.0f ? v : 0.0f;
  if (lq < 8) {
    int t = row & (S_LEN - 1);
    int b = row >> 12;
    int e = (S_LEN - 1) - t;
    int p = lq;
    if (e >= p) {
      int d = e - p;
      cp[((size_t)(b * 8 + p) * CPROWS + (d >> 3)) * 8 + (d & 7)] = f2bf(v);
    }
  }
}

// K2: Gt[n][t] = sum_q Wh[q,n]*H[q,t] (unchanged)
__global__ __launch_bounds__(256) void k_g(const short* __restrict__ wht,
                                           const short* __restrict__ Ht,
                                           short* __restrict__ Gt) {
  int nt = blockIdx.x & 1, tt = blockIdx.x >> 1;
  int n0 = nt << 7, t0 = tt << 7;
  int tid = threadIdx.x;
  int lane = tid & 63, wid = tid >> 6;
  int wr = wid >> 1, wc = wid & 1;
  int lm = lane & 15, kg = lane >> 4;

  const short* Abase = wht + (size_t)(n0 + wr * 64 + lm) * 384 + 8 * kg;
  const short* Bbase = Ht  + (size_t)(t0 + wc * 64 + lm) * 256 + 8 * kg;

  f32x4 acc[4][4];
  #pragma unroll
  for (int ii = 0; ii < 4; ++ii)
    #pragma unroll
    for (int jn = 0; jn < 4; ++jn)
      acc[ii][jn] = (f32x4){0.0f, 0.0f, 0.0f, 0.0f};

  #pragma unroll
  for (int c = 0; c < 4; ++c) {
    short8 a[8], bf[8];
    #pragma unroll
    for (int mf = 0; mf < 4; ++mf)
      #pragma unroll
      for (int ks = 0; ks < 2; ++ks)
        a[mf * 2 + ks] = *(const short8*)(Abase + mf * 16 * 384 + c * 64 + ks * 32);
    #pragma unroll
    for (int nf = 0; nf < 4; ++nf)
      #pragma unroll
      for (int ks = 0; ks < 2; ++ks)
        bf[nf * 2 + ks] = *(const short8*)(Bbase + nf * 16 * 256 + c * 64 + ks * 32);
    #pragma unroll
    for (int ks = 0; ks < 2; ++ks)
      #pragma unroll
      for (int mf = 0; mf < 4; ++mf)
        #pragma unroll
        for (int nf = 0; nf < 4; ++nf)
          MFMA(acc[mf][nf], a[mf * 2 + ks], bf[nf * 2 + ks]);
  }

  #pragma unroll
  for (int mf = 0; mf < 4; ++mf)
    #pragma unroll
    for (int nf = 0; nf < 4; ++nf)
      #pragma unroll
      for (int j = 0; j < 4; ++j) {
        int n = n0 + wr * 64 + mf * 16 + kg * 4 + j;
        int t = t0 + wc * 64 + nf * 16 + lm;
        Gt[(size_t)n * S_LEN + t] = f2bf(acc[mf][nf][j]);
      }
}

// K3 fused (R17 verbatim — best measured: 47.3us)
__global__ __launch_bounds__(256, 2) void k_fused(const short* __restrict__ cp,
                                                  const short* __restrict__ Gt,
                                                  const short* __restrict__ xb,
                                                  const short* __restrict__ wht,
                                                  const float* __restrict__ bh,
                                                  float* __restrict__ out) {
  __shared__ __attribute__((aligned(16))) short Bt[4][64 * 128];  // 64 KB
  __shared__ __attribute__((aligned(16))) short Aw[4][2048];      // 16 KB

  int i = blockIdx.x;                 // 512 = kk(16) * nq(4) * b(8)
  int kk = i >> 5;
  int nq = (i >> 3) & 3;
  int b  = i & 7;
  int n0 = nq << 6;

  int tid = threadIdx.x;
  int lane = tid & 63, wid = tid >> 6;
  int wr = wid >> 1, wc = wid & 1;      // wave tile 64(s) x 32(n)
  int lm = lane & 15, kg = lane >> 4;
  int l3 = lane >> 3, l7 = lane & 7;
  int lm7 = lm & 7;

  const short* bS0 = Gt + (size_t)(n0 + wid * 16 + kg) * S_LEN + ((lm ^ kg) << 3);
  const short* bS1 = Gt + (size_t)(n0 + wid * 16 + 4 + kg) * S_LEN + ((lm ^ (kg | 4)) << 3);

  int dbase = 127 - 64 * wr - lm + 8 * kg;
  int aof[10];
  #pragma unroll
  for (int v = 0; v < 10; ++v) {
    int d = dbase + 16 * v - 48;
    aof[v] = ((d & ~7) | ((d & 7) ^ ((d >> 3) & 7))) << 3;   // shorts
  }

  int bof[8];
  #pragma unroll
  for (int nf = 0; nf < 2; ++nf)
    #pragma unroll
    for (int ks = 0; ks < 4; ++ks)
      bof[nf * 4 + ks] = (wc * 32 + nf * 16 + lm) * 128 + (((4 * ks + kg) ^ lm7) << 3);

  int xof[4][2];
  #pragma unroll
  for (int mf = 0; mf < 4; ++mf)
    #pragma unroll
    for (int ks = 0; ks < 2; ++ks)
      xof[mf][ks] = (wr * 64 + mf * 16 + lm) * 64 + (((4 * ks + kg) ^ lm7) << 3);

  for (int ph = 0; ph < 2; ++ph) {
    int st = ph ? kk : (31 - kk);
    int s0 = st << 7;
    int asbase = 496 - 16 * st;
    const short* aSrc = cp + ((size_t)(b * 8 + (l7 ^ l3)) * CPROWS + asbase + wid * 8 + l3) * 8;
    const short* xS = xb + (size_t)(b * S_LEN + s0 + wid * 32 + l3) * 128 + ((l7 ^ l3) << 3);

    int NT = st + 1;           // Toeplitz BK-128 chunks
    int NC = NT + 2;           // + 2 x BK-64 chunks

    f32x4 acc[4][2];
    #pragma unroll
    for (int ii = 0; ii < 4; ++ii)
      #pragma unroll
      for (int jn = 0; jn < 2; ++jn)
        acc[ii][jn] = (f32x4){0.0f, 0.0f, 0.0f, 0.0f};

    auto STAGE = [&](int cc) {
      int slot = cc & 3;
      if (cc < NT) {
        int coff = cc * 128;
        gload16(bS0 + coff,                      &Bt[slot][(wid * 16) * 128]);
        gload16(bS1 + coff,                      &Bt[slot][(wid * 16 + 4) * 128]);
        gload16(bS0 + (size_t)8 * S_LEN + coff,  &Bt[slot][(wid * 16 + 8) * 128]);
        gload16(bS1 + (size_t)8 * S_LEN + coff,  &Bt[slot][(wid * 16 + 12) * 128]);
        gload16(aSrc + coff,                     &Aw[slot][wid * 512]);
      } else {
        int dc = cc - NT;
        #pragma unroll
        for (int jj = 0; jj < 4; ++jj)
          gload16(xS + (size_t)(8 * jj) * 128 + dc * 64, &Bt[slot][(wid * 32 + 8 * jj) * 64]);
        gload16(aSrc, &Aw[slot][wid * 512]);   // dummy: uniform 5 loads/chunk
      }
    };

    if (ph) asm volatile("s_waitcnt vmcnt(0) lgkmcnt(0)\n\ts_barrier" ::: "memory");
    STAGE(0);
    STAGE(1);

    for (int c = 0; c < NC; ++c) {
      if (c + 2 < NC) {
        STAGE(c + 2);
        asm volatile("s_waitcnt vmcnt(10) lgkmcnt(0)\n\ts_barrier" ::: "memory");
      } else if (c + 1 < NC) {
        asm volatile("s_waitcnt vmcnt(5) lgkmcnt(0)\n\ts_barrier" ::: "memory");
      } else {
        asm volatile("s_waitcnt vmcnt(0) lgkmcnt(0)\n\ts_barrier" ::: "memory");
      }

      if (c < NT) {
        const short* AwB = &Aw[c & 3][0];
        const short* BtB = &Bt[c & 3][0];
        short8 A10[10];
        #pragma unroll
        for (int v = 0; v < 10; ++v) A10[v] = *(const short8*)(AwB + aof[v]);
        short8 Bf[8];
        #pragma unroll
        for (int ii = 0; ii < 8; ++ii) Bf[ii] = *(const short8*)(BtB + bof[ii]);
        __builtin_amdgcn_s_setprio(1);
        #pragma unroll
        for (int ks = 0; ks < 4; ++ks)
          #pragma unroll
          for (int mf = 0; mf < 4; ++mf)
            #pragma unroll
            for (int nf = 0; nf < 2; ++nf)
              MFMA(acc[mf][nf], A10[2 * ks - mf + 3], Bf[nf * 4 + ks]);
        __builtin_amdgcn_s_setprio(0);
      } else {
        int dc = c - NT;
        const short* BtB = &Bt[c & 3][0];
        short8 Ax[4][2];
        #pragma unroll
        for (int mf = 0; mf < 4; ++mf)
          #pragma unroll
          for (int ks = 0; ks < 2; ++ks)
            Ax[mf][ks] = *(const short8*)(BtB + xof[mf][ks]);
        short8 Bx[2][2];
        #pragma unroll
        for (int ks = 0; ks < 2; ++ks)
          #pragma unroll
          for (int nf = 0; nf < 2; ++nf)
            Bx[ks][nf] = *(const short8*)(wht + (size_t)(n0 + wc * 32 + nf * 16 + lm) * 384
                                          + 256 + dc * 64 + ks * 32 + kg * 8);
        __builtin_amdgcn_s_setprio(1);
        #pragma unroll
        for (int ks = 0; ks < 2; ++ks)
          #pragma unroll
          for (int mf = 0; mf < 4; ++mf)
            #pragma unroll
            for (int nf = 0; nf < 2; ++nf)
              MFMA(acc[mf][nf], Ax[mf][ks], Bx[ks][nf]);
        __builtin_amdgcn_s_setprio(0);
      }
    }

    // Epilogue: bias + relu + f32 store (+ h_n for s==4095)
    #pragma unroll
    for (int mf = 0; mf < 4; ++mf)
      #pragma unroll
      for (int nf = 0; nf < 2; ++nf) {
        int n = n0 + wc * 32 + nf * 16 + lm;
        float bias = bh[n];
        #pragma unroll
        for (int j2 = 0; j2 < 4; ++j2) {
          int s = s0 + wr * 64 + mf * 16 + kg * 4 + j2;
          float v = acc[mf][nf][j2] + bias;
          v = v > 0.0f ? v : 0.0f;
          out[(size_t)(b * S_LEN + s) * 256 + n] = v;
          if (s == S_LEN - 1)
            out[HN_OFF + b * 256 + n] = v;
        }
      }
  }
}

extern "C" void kernel_launch(void* const* d_in, const int* in_sizes, int n_in,
                              void* d_out, int out_size, void* d_ws, size_t ws_size,
                              hipStream_t stream) {
  const float* x  = (const float*)d_in[0];
  const float* Wu = (const float*)d_in[1];
  const float* bu = (const float*)d_in[2];
  const float* Wh = (const float*)d_in[3];
  const float* bh = (const float*)d_in[4];
  const float* H  = (const float*)d_in[5];
  float* out = (float*)d_out;

  char* ws = (char*)d_ws;
  short* cp  = (short*)(ws);                       // 557056 B
  short* wht = (short*)(ws + 557056);              // 196608 B
  short* xb  = (short*)(ws + 753664);              // 8388608 B
  short* Ht  = (short*)(ws + 9142272);             // 2097152 B
  short* Gt  = (short*)(ws + 11239424);            // 2097152 B (end 13336576)

  k_prep<<<2400, 256, 0, stream>>>(x, Wu, bu, H, Wh, cp, xb, Ht, wht);
  k_g   <<<64,   256, 0, stream>>>(wht, Ht, Gt);
  k_fused<<<512, 256, 0, stream>>>(cp, Gt, xb, wht, bh, out);
}